// Round 6
// baseline (472.339 us; speedup 1.0000x reference)
//
#include <hip/hip_runtime.h>

typedef _Float16 h8  __attribute__((ext_vector_type(8)));
typedef _Float16 hh4 __attribute__((ext_vector_type(4)));
typedef float    f4  __attribute__((ext_vector_type(4)));

#define TT 1024
#define FF 64
#define NTH 512
#define GRP 16
#define NGRP (TT / GRP)
#define K2 2.8853900817779268f   // 2/ln2

// swizzle for x_s only: elem ^= (row&7)<<3
#define HSWZ(r, e) ((e) ^ (((r) & 7) << 3))

__device__ __forceinline__ float tanh0(float z) {
  float e = __builtin_amdgcn_exp2f(z * K2);
  return __builtin_fmaf(-2.0f, __builtin_amdgcn_rcpf(e + 1.0f), 1.0f);
}

#define MFMA __builtin_amdgcn_mfma_f32_16x16x32_f16
#define FENCE() __builtin_amdgcn_sched_barrier(0)

// One persistent block per 2 batch rows. 8 waves; wave wv owns hidden cols
// [wv*16,wv*16+16) of each gate. Batch row r at M-row 4r (C: row=4*(lane>>4)+reg
// -> row r in lane-group r, reg 0). h compact in LDS (broadcast reads for
// non-owner lanes). x@W hoisted per GRP steps into fp32 zx_s.
// Step schedule: k0,k1 f-major (4 independent chains, pipe fed), then staggered
// k2/k3 tail with fences so tanh_i/f overlap gate-g/o MFMA issues.
__global__ __launch_bounds__(NTH, 2) void lstm_persist(
    const float* __restrict__ X, const float* __restrict__ W,
    const float* __restrict__ U, const float* __restrict__ bias,
    const float* __restrict__ Wfc, const float* __restrict__ bfcp,
    float* __restrict__ out)
{
  const int tid = threadIdx.x;
  const int wv = tid >> 6, ln = tid & 63;
  const int l15 = ln & 15, lg = ln >> 4;
  const int row0 = blockIdx.x * 2;
  const int ncol = wv * 16 + l15;

  __shared__ __align__(16) _Float16 h_s[2][384];      // rows 0,1 live; row2 scratch
  __shared__ __align__(16) _Float16 x_s[32 * 64];     // 4KB, row m = 2*tt + r (swizzled)
  __shared__ __align__(16) float    zx_s[32 * 512];   // 64KB fp32 [m][ncol*4+gate]
  __shared__ float red[8][2];

  // ---- persistent weight fragments (fp16, k-map k = 32f + 8lg + e, shared by A&B) ----
  h8 uf[4][4], wf4[4][2];
  f4 bias4[4];
#pragma unroll
  for (int g = 0; g < 4; ++g) {
    const int n = g * 128 + ncol;
#pragma unroll
    for (int f = 0; f < 4; ++f) {
      h8 v;
#pragma unroll
      for (int e = 0; e < 8; ++e) v[e] = (_Float16)U[(32 * f + 8 * lg + e) * 512 + n];
      uf[g][f] = v;
    }
#pragma unroll
    for (int f = 0; f < 2; ++f) {
      h8 v;
#pragma unroll
      for (int e = 0; e < 8; ++e) v[e] = (_Float16)W[(32 * f + 8 * lg + e) * 512 + n];
      wf4[g][f] = v;
    }
    const float bv = bias[n];
    f4 b4 = {bv, bv, bv, bv};
    bias4[g] = b4;
  }
  const float wfc = Wfc[ncol];

  // h-fragment offsets: real for l15==0 (row0) / l15==4 (row1); others -> 0 (broadcast)
  int hofs[4];
#pragma unroll
  for (int f = 0; f < 4; ++f) {
    const int base = 32 * f + 8 * lg;
    hofs[f] = (l15 == 0) ? base : (l15 == 4) ? 128 + base : 0;
  }
  // bulk x-fragment offsets (x_s swizzled): A rows m = mt*16 + l15
  int bxofs[2][2];
#pragma unroll
  for (int mt = 0; mt < 2; ++mt)
#pragma unroll
    for (int f = 0; f < 2; ++f)
      bxofs[mt][f] = HSWZ(l15, (mt * 16 + l15) * 64 + 32 * f + 8 * lg);

  // zx per-step read (f32): lane needs m=2S+lg at ncol*4; lg>=2 -> broadcast 0
  const int zofs  = (lg < 2) ? (lg * 512 + ncol * 4) : 0;
  const int zwofs = ncol * 4;
  const int hwofs = (lg < 2) ? (lg * 128 + ncol) : (256 + ncol);  // scratch row lg>=2

  // x staging map: thread -> (m = 2*tt + r, 4 consecutive k)
  const int sm = tid >> 4;
  const int sk = (tid & 15) * 4;
  const int sxofs = HSWZ(sm, sm * 64 + sk);
  const size_t xoff0 = (size_t)(row0 + (sm & 1)) * (TT * FF) + (size_t)(sm >> 1) * FF + sk;

  // zero compact h (both buffers, incl. scratch rows)
  for (int i = tid; i < 2 * 384; i += NTH) ((_Float16*)h_s)[i] = (_Float16)0.0f;

  f4 xg = *(const f4*)(X + xoff0);   // group-0 x chunk in regs
  float cc = 0.f;
  const f4 zq = {0.f, 0.f, 0.f, 0.f};
  f4 qc;
  __syncthreads();

#define STEP(S, CUR, NXT, DOPF) {                                             \
    const _Float16* hb = &h_s[CUR][0];                                        \
    h8 ha0 = *(const h8*)(hb + hofs[0]);                                      \
    h8 ha1 = *(const h8*)(hb + hofs[1]);                                      \
    h8 ha2 = *(const h8*)(hb + hofs[2]);                                      \
    h8 ha3 = *(const h8*)(hb + hofs[3]);                                      \
    /* k0,k1 f-major: 4 independent chains, matrix pipe fed */                \
    f4 a0 = MFMA(ha0, uf[0][0], zq, 0, 0, 0);                                 \
    f4 a1 = MFMA(ha0, uf[1][0], zq, 0, 0, 0);                                 \
    f4 a2 = MFMA(ha0, uf[2][0], zq, 0, 0, 0);                                 \
    f4 a3 = MFMA(ha0, uf[3][0], zq, 0, 0, 0);                                 \
    a0 = MFMA(ha1, uf[0][1], a0, 0, 0, 0);                                    \
    a1 = MFMA(ha1, uf[1][1], a1, 0, 0, 0);                                    \
    a2 = MFMA(ha1, uf[2][1], a2, 0, 0, 0);                                    \
    a3 = MFMA(ha1, uf[3][1], a3, 0, 0, 0);                                    \
    /* staggered tail: finish i, f early; overlap their tanh with g,o MFMAs */\
    a0 = MFMA(ha2, uf[0][2], a0, 0, 0, 0);                                    \
    a0 = MFMA(ha3, uf[0][3], a0, 0, 0, 0);                                    \
    a1 = MFMA(ha2, uf[1][2], a1, 0, 0, 0);                                    \
    a1 = MFMA(ha3, uf[1][3], a1, 0, 0, 0);                                    \
    FENCE();                                                                  \
    float ti = tanh0(a0[0] + qc[0]);                                          \
    FENCE();                                                                  \
    a2 = MFMA(ha2, uf[2][2], a2, 0, 0, 0);                                    \
    a2 = MFMA(ha3, uf[2][3], a2, 0, 0, 0);                                    \
    FENCE();                                                                  \
    float tf = tanh0(a1[0] + qc[1]);                                          \
    FENCE();                                                                  \
    a3 = MFMA(ha2, uf[3][2], a3, 0, 0, 0);                                    \
    a3 = MFMA(ha3, uf[3][3], a3, 0, 0, 0);                                    \
    FENCE();                                                                  \
    float tg = tanh0(a2[0] + qc[2]);                                          \
    cc = __builtin_fmaf(tf, cc, ti * tg);                                     \
    float tcc = tanh0(cc);                  /* ready before a3 lands */       \
    float to = tanh0(a3[0] + qc[3]);                                          \
    float hv = to * tcc;                                                      \
    h_s[NXT][hwofs] = (_Float16)hv;                                           \
    if (DOPF) qc = *(const f4*)(&zx_s[zofs + ((S) + 1) * 1024]);              \
    __syncthreads();                                                          \
  }

#pragma unroll 1
  for (int grp = 0; grp < NGRP; ++grp) {
    // ---- stage this group's x chunk (regs -> LDS, fp16) ----
    {
      hh4 pk;
#pragma unroll
      for (int j = 0; j < 4; ++j) pk[j] = (_Float16)xg[j];
      *(hh4*)(&x_s[sxofs]) = pk;
    }
    __syncthreads();

    // ---- bulk: Zx[m][*] = x_chunk @ W + bias (fp32 out), m = 0..31 ----
    h8 xa00 = *(const h8*)(&x_s[bxofs[0][0]]);
    h8 xa01 = *(const h8*)(&x_s[bxofs[0][1]]);
    h8 xa10 = *(const h8*)(&x_s[bxofs[1][0]]);
    h8 xa11 = *(const h8*)(&x_s[bxofs[1][1]]);
    f4 b00 = MFMA(xa00, wf4[0][0], bias4[0], 0, 0, 0);
    f4 b01 = MFMA(xa00, wf4[1][0], bias4[1], 0, 0, 0);
    f4 b02 = MFMA(xa00, wf4[2][0], bias4[2], 0, 0, 0);
    f4 b03 = MFMA(xa00, wf4[3][0], bias4[3], 0, 0, 0);
    b00 = MFMA(xa01, wf4[0][1], b00, 0, 0, 0);
    b01 = MFMA(xa01, wf4[1][1], b01, 0, 0, 0);
    b02 = MFMA(xa01, wf4[2][1], b02, 0, 0, 0);
    b03 = MFMA(xa01, wf4[3][1], b03, 0, 0, 0);
    f4 b10 = MFMA(xa10, wf4[0][0], bias4[0], 0, 0, 0);
    f4 b11 = MFMA(xa10, wf4[1][0], bias4[1], 0, 0, 0);
    f4 b12 = MFMA(xa10, wf4[2][0], bias4[2], 0, 0, 0);
    f4 b13 = MFMA(xa10, wf4[3][0], bias4[3], 0, 0, 0);
    b10 = MFMA(xa11, wf4[0][1], b10, 0, 0, 0);
    b11 = MFMA(xa11, wf4[1][1], b11, 0, 0, 0);
    b12 = MFMA(xa11, wf4[2][1], b12, 0, 0, 0);
    b13 = MFMA(xa11, wf4[3][1], b13, 0, 0, 0);
    // packed scatter: m = mt*16 + 4lg + j, 4 gates -> one ds_write_b128
#pragma unroll
    for (int j = 0; j < 4; ++j) {
      f4 p0 = {b00[j], b01[j], b02[j], b03[j]};
      *(f4*)(&zx_s[(0 * 16 + 4 * lg + j) * 512 + zwofs]) = p0;
      f4 p1 = {b10[j], b11[j], b12[j], b13[j]};
      *(f4*)(&zx_s[(1 * 16 + 4 * lg + j) * 512 + zwofs]) = p1;
    }
    // prefetch next group's x into regs (covered by the 16 steps below)
    {
      const int t0n = (grp + 1 < NGRP ? grp + 1 : grp) * GRP;
      xg = *(const f4*)(X + xoff0 + (size_t)t0n * FF);
    }
    __syncthreads();
    qc = *(const f4*)(&zx_s[zofs]);   // step-0 zx

    // ---- 16 recurrent steps ----
#pragma unroll
    for (int s2 = 0; s2 < 8; ++s2) {
      STEP(2 * s2,     0, 1, 1)
      STEP(2 * s2 + 1, 1, 0, (2 * s2 + 1) != (GRP - 1))
    }
  }
#undef STEP

  // ---- epilogue: y[r] = h_last[r,:] @ Wfc + bfc  (h_last in buffer 0) ----
  float hw0 = (float)h_s[0][ncol];
  float hw1 = (float)h_s[0][128 + ncol];
  float p0 = hw0 * wfc;
  float p1 = hw1 * wfc;
#pragma unroll
  for (int m = 1; m < 16; m <<= 1) {
    p0 += __shfl_xor(p0, m, 16);
    p1 += __shfl_xor(p1, m, 16);
  }
  if (ln == 0) { red[wv][0] = p0; red[wv][1] = p1; }
  __syncthreads();
  if (tid < 2) {
    float y = bfcp[0];
#pragma unroll
    for (int w2 = 0; w2 < 8; ++w2) y += red[w2][tid];
    out[row0 + tid] = y;
  }
}

extern "C" void kernel_launch(void* const* d_in, const int* in_sizes, int n_in,
                              void* d_out, int out_size, void* d_ws, size_t ws_size,
                              hipStream_t stream) {
  const float* x   = (const float*)d_in[0];
  const float* W   = (const float*)d_in[1];
  const float* U   = (const float*)d_in[2];
  const float* b   = (const float*)d_in[3];
  const float* Wfc = (const float*)d_in[4];
  const float* bfc = (const float*)d_in[5];
  float* out = (float*)d_out;
  hipLaunchKernelGGL(lstm_persist, dim3(256), dim3(NTH), 0, stream,
                     x, W, U, b, Wfc, bfc, out);
}

// Round 8
// 461.887 us; speedup vs baseline: 1.0226x; 1.0226x over previous
//
#include <hip/hip_runtime.h>

typedef _Float16 h8  __attribute__((ext_vector_type(8)));
typedef _Float16 hh4 __attribute__((ext_vector_type(4)));
typedef float    f4  __attribute__((ext_vector_type(4)));

#define TT 1024
#define FF 64
#define NTH 512
#define GRP 16
#define NGRP (TT / GRP)
#define K2 2.8853900817779268f   // 2/ln2

// swizzle for x_s only: elem ^= (row&7)<<3
#define HSWZ(r, e) ((e) ^ (((r) & 7) << 3))

__device__ __forceinline__ float tanh0(float z) {
  float e = __builtin_amdgcn_exp2f(z * K2);
  return __builtin_fmaf(-2.0f, __builtin_amdgcn_rcpf(e + 1.0f), 1.0f);
}

#define MFMA __builtin_amdgcn_mfma_f32_16x16x32_f16
#define FENCE() __builtin_amdgcn_sched_barrier(0)

// One persistent block per 2 batch rows. 8 waves; wave wv owns hidden cols
// [wv*16,wv*16+16) of each gate. Batch row r at M-row 4r (C: row=4*(lane>>4)+reg
// -> row r in lane-group r, reg 0). h compact in LDS (broadcast reads for
// non-owner lanes). x@W hoisted per GRP steps into fp16 zx_s.
// ODD waves run at s_setprio(1): they win matrix-pipe arbitration, finish
// their 16 MFMAs first and run tanh on the VALU pipe WHILE even waves'
// MFMAs occupy the matrix pipe -> cross-pipe overlap (m114) instead of
// lockstep phase serialization.
__global__ __launch_bounds__(NTH, 2) void lstm_persist(
    const float* __restrict__ X, const float* __restrict__ W,
    const float* __restrict__ U, const float* __restrict__ bias,
    const float* __restrict__ Wfc, const float* __restrict__ bfcp,
    float* __restrict__ out)
{
  const int tid = threadIdx.x;
  const int wv = tid >> 6, ln = tid & 63;
  const int l15 = ln & 15, lg = ln >> 4;
  const int row0 = blockIdx.x * 2;
  const int ncol = wv * 16 + l15;

  __shared__ __align__(16) _Float16 h_s[2][384];      // rows 0,1 live; row2 scratch
  __shared__ __align__(16) _Float16 x_s[32 * 64];     // 4KB row m = 2*tt + r (swizzled)
  __shared__ __align__(16) _Float16 zx_s[32 * 512];   // 32KB [m][ncol*4+gate]
  __shared__ float red[8][2];

  // ---- persistent weight fragments (fp16, k-map k = 32f + 8lg + e, shared by A&B) ----
  h8 uf[4][4], wf4[4][2];
  f4 bias4[4];
#pragma unroll
  for (int g = 0; g < 4; ++g) {
    const int n = g * 128 + ncol;
#pragma unroll
    for (int f = 0; f < 4; ++f) {
      h8 v;
#pragma unroll
      for (int e = 0; e < 8; ++e) v[e] = (_Float16)U[(32 * f + 8 * lg + e) * 512 + n];
      uf[g][f] = v;
    }
#pragma unroll
    for (int f = 0; f < 2; ++f) {
      h8 v;
#pragma unroll
      for (int e = 0; e < 8; ++e) v[e] = (_Float16)W[(32 * f + 8 * lg + e) * 512 + n];
      wf4[g][f] = v;
    }
    const float bv = bias[n];
    f4 b4 = {bv, bv, bv, bv};
    bias4[g] = b4;
  }
  const float wfc = Wfc[ncol];

  // h-fragment offsets: real for l15==0 (row0) / l15==4 (row1); others -> 0 (broadcast)
  int hofs[4];
#pragma unroll
  for (int f = 0; f < 4; ++f) {
    const int base = 32 * f + 8 * lg;
    hofs[f] = (l15 == 0) ? base : (l15 == 4) ? 128 + base : 0;
  }
  // bulk x-fragment offsets (x_s swizzled): A rows m = mt*16 + l15
  int bxofs[2][2];
#pragma unroll
  for (int mt = 0; mt < 2; ++mt)
#pragma unroll
    for (int f = 0; f < 2; ++f)
      bxofs[mt][f] = HSWZ(l15, (mt * 16 + l15) * 64 + 32 * f + 8 * lg);

  // zx per-step read: lane needs m=2S+lg at ncol*4; lg>=2 -> broadcast 0
  const int zofs  = (lg < 2) ? (lg * 512 + ncol * 4) : 0;
  const int zwofs = ncol * 4;
  const int hwofs = (lg < 2) ? (lg * 128 + ncol) : (256 + ncol);  // scratch row lg>=2

  // x staging map: thread -> (m = 2*tt + r, 4 consecutive k)
  const int sm = tid >> 4;
  const int sk = (tid & 15) * 4;
  const int sxofs = HSWZ(sm, sm * 64 + sk);
  const size_t xoff0 = (size_t)(row0 + (sm & 1)) * (TT * FF) + (size_t)(sm >> 1) * FF + sk;

  // zero compact h (both buffers, incl. scratch rows)
  for (int i = tid; i < 2 * 384; i += NTH) ((_Float16*)h_s)[i] = (_Float16)0.0f;

  // static phase-skew: odd waves win pipe arbitration
  if (wv & 1) __builtin_amdgcn_s_setprio(1);

  f4 xg = *(const f4*)(X + xoff0);   // group-0 x chunk in regs
  float cc = 0.f;
  const f4 zq = {0.f, 0.f, 0.f, 0.f};
  hh4 q4cur;
  __syncthreads();

#define STEP(S, CUR, NXT, DOPF) {                                             \
    const _Float16* hb = &h_s[CUR][0];                                        \
    h8 ha0 = *(const h8*)(hb + hofs[0]);                                      \
    h8 ha1 = *(const h8*)(hb + hofs[1]);                                      \
    h8 ha2 = *(const h8*)(hb + hofs[2]);                                      \
    h8 ha3 = *(const h8*)(hb + hofs[3]);                                      \
    f4 a0 = MFMA(ha0, uf[0][0], zq, 0, 0, 0);                                 \
    a0 = MFMA(ha1, uf[0][1], a0, 0, 0, 0);                                    \
    a0 = MFMA(ha2, uf[0][2], a0, 0, 0, 0);                                    \
    a0 = MFMA(ha3, uf[0][3], a0, 0, 0, 0);                                    \
    float ti = tanh0(a0[0] + (float)q4cur[0]);                                \
    FENCE();                                                                  \
    f4 a1 = MFMA(ha0, uf[1][0], zq, 0, 0, 0);                                 \
    a1 = MFMA(ha1, uf[1][1], a1, 0, 0, 0);                                    \
    a1 = MFMA(ha2, uf[1][2], a1, 0, 0, 0);                                    \
    a1 = MFMA(ha3, uf[1][3], a1, 0, 0, 0);                                    \
    float tf = tanh0(a1[0] + (float)q4cur[1]);                                \
    FENCE();                                                                  \
    f4 a2 = MFMA(ha0, uf[2][0], zq, 0, 0, 0);                                 \
    a2 = MFMA(ha1, uf[2][1], a2, 0, 0, 0);                                    \
    a2 = MFMA(ha2, uf[2][2], a2, 0, 0, 0);                                    \
    a2 = MFMA(ha3, uf[2][3], a2, 0, 0, 0);                                    \
    float tg = tanh0(a2[0] + (float)q4cur[2]);                                \
    cc = __builtin_fmaf(tf, cc, ti * tg);                                     \
    FENCE();                                                                  \
    f4 a3 = MFMA(ha0, uf[3][0], zq, 0, 0, 0);                                 \
    a3 = MFMA(ha1, uf[3][1], a3, 0, 0, 0);                                    \
    a3 = MFMA(ha2, uf[3][2], a3, 0, 0, 0);                                    \
    a3 = MFMA(ha3, uf[3][3], a3, 0, 0, 0);                                    \
    float to = tanh0(a3[0] + (float)q4cur[3]);                                \
    float hv = to * tanh0(cc);                                                \
    h_s[NXT][hwofs] = (_Float16)hv;                                           \
    if (DOPF) q4cur = *(const hh4*)(&zx_s[zofs + ((S) + 1) * 1024]);          \
    __syncthreads();                                                          \
  }

#pragma unroll 1
  for (int grp = 0; grp < NGRP; ++grp) {
    // ---- stage this group's x chunk (regs -> LDS, fp16) ----
    {
      hh4 pk;
#pragma unroll
      for (int j = 0; j < 4; ++j) pk[j] = (_Float16)xg[j];
      *(hh4*)(&x_s[sxofs]) = pk;
    }
    __syncthreads();

    // ---- bulk: Zx[m][*] = x_chunk @ W + bias, m = 0..31 ----
    h8 xa00 = *(const h8*)(&x_s[bxofs[0][0]]);
    h8 xa01 = *(const h8*)(&x_s[bxofs[0][1]]);
    h8 xa10 = *(const h8*)(&x_s[bxofs[1][0]]);
    h8 xa11 = *(const h8*)(&x_s[bxofs[1][1]]);
    f4 b00 = MFMA(xa00, wf4[0][0], bias4[0], 0, 0, 0);
    f4 b01 = MFMA(xa00, wf4[1][0], bias4[1], 0, 0, 0);
    f4 b02 = MFMA(xa00, wf4[2][0], bias4[2], 0, 0, 0);
    f4 b03 = MFMA(xa00, wf4[3][0], bias4[3], 0, 0, 0);
    b00 = MFMA(xa01, wf4[0][1], b00, 0, 0, 0);
    b01 = MFMA(xa01, wf4[1][1], b01, 0, 0, 0);
    b02 = MFMA(xa01, wf4[2][1], b02, 0, 0, 0);
    b03 = MFMA(xa01, wf4[3][1], b03, 0, 0, 0);
    f4 b10 = MFMA(xa10, wf4[0][0], bias4[0], 0, 0, 0);
    f4 b11 = MFMA(xa10, wf4[1][0], bias4[1], 0, 0, 0);
    f4 b12 = MFMA(xa10, wf4[2][0], bias4[2], 0, 0, 0);
    f4 b13 = MFMA(xa10, wf4[3][0], bias4[3], 0, 0, 0);
    b10 = MFMA(xa11, wf4[0][1], b10, 0, 0, 0);
    b11 = MFMA(xa11, wf4[1][1], b11, 0, 0, 0);
    b12 = MFMA(xa11, wf4[2][1], b12, 0, 0, 0);
    b13 = MFMA(xa11, wf4[3][1], b13, 0, 0, 0);
    // packed scatter: m = mt*16 + 4lg + j, 4 gates -> one ds_write_b64
#pragma unroll
    for (int j = 0; j < 4; ++j) {
      hh4 p0; p0[0] = (_Float16)b00[j]; p0[1] = (_Float16)b01[j];
              p0[2] = (_Float16)b02[j]; p0[3] = (_Float16)b03[j];
      *(hh4*)(&zx_s[(0 * 16 + 4 * lg + j) * 512 + zwofs]) = p0;
      hh4 p1; p1[0] = (_Float16)b10[j]; p1[1] = (_Float16)b11[j];
              p1[2] = (_Float16)b12[j]; p1[3] = (_Float16)b13[j];
      *(hh4*)(&zx_s[(1 * 16 + 4 * lg + j) * 512 + zwofs]) = p1;
    }
    // prefetch next group's x into regs (covered by the 16 steps below)
    {
      const int t0n = (grp + 1 < NGRP ? grp + 1 : grp) * GRP;
      xg = *(const f4*)(X + xoff0 + (size_t)t0n * FF);
    }
    __syncthreads();
    q4cur = *(const hh4*)(&zx_s[zofs]);   // step-0 zx

    // ---- 16 recurrent steps ----
#pragma unroll
    for (int s2 = 0; s2 < 8; ++s2) {
      STEP(2 * s2,     0, 1, 1)
      STEP(2 * s2 + 1, 1, 0, (2 * s2 + 1) != (GRP - 1))
    }
  }
#undef STEP

  // ---- epilogue: y[r] = h_last[r,:] @ Wfc + bfc  (h_last in buffer 0) ----
  float hw0 = (float)h_s[0][ncol];
  float hw1 = (float)h_s[0][128 + ncol];
  float p0 = hw0 * wfc;
  float p1 = hw1 * wfc;
#pragma unroll
  for (int m = 1; m < 16; m <<= 1) {
    p0 += __shfl_xor(p0, m, 16);
    p1 += __shfl_xor(p1, m, 16);
  }
  if (ln == 0) { red[wv][0] = p0; red[wv][1] = p1; }
  __syncthreads();
  if (tid < 2) {
    float y = bfcp[0];
#pragma unroll
    for (int w2 = 0; w2 < 8; ++w2) y += red[w2][tid];
    out[row0 + tid] = y;
  }
}

extern "C" void kernel_launch(void* const* d_in, const int* in_sizes, int n_in,
                              void* d_out, int out_size, void* d_ws, size_t ws_size,
                              hipStream_t stream) {
  const float* x   = (const float*)d_in[0];
  const float* W   = (const float*)d_in[1];
  const float* U   = (const float*)d_in[2];
  const float* b   = (const float*)d_in[3];
  const float* Wfc = (const float*)d_in[4];
  const float* bfc = (const float*)d_in[5];
  float* out = (float*)d_out;
  hipLaunchKernelGGL(lstm_persist, dim3(256), dim3(NTH), 0, stream,
                     x, W, U, b, Wfc, bfc, out);
}